// Round 3
// baseline (3179.081 us; speedup 1.0000x reference)
//
#include <hip/hip_runtime.h>

#define NN 100000
#define NE 3200000
#define NG 512
#define NBUCK 1563        // ceil(NN / 64)
#define ES_CAP (NE + 8 * NBUCK)
#define BN_EPS 1e-5f

// ================= node-degree histogram =================
__global__ __launch_bounds__(256) void k_hist(const int* __restrict__ dst, int* __restrict__ cnt) {
    int stride = gridDim.x * 256;
    for (int e = blockIdx.x * 256 + threadIdx.x; e < NE; e += stride)
        atomicAdd(&cnt[dst[e]], 1);
}

// ================= node-level scan (for dinv + bucket sizes) =================
__global__ __launch_bounds__(256) void k_scan1(const int* __restrict__ cnt, int* __restrict__ offs,
                                               int* __restrict__ bsum) {
    __shared__ int sh[256];
    int t = threadIdx.x;
    int base = blockIdx.x * 1024 + t * 4;
    int v[4];
#pragma unroll
    for (int j = 0; j < 4; j++) v[j] = (base + j < NN) ? cnt[base + j] : 0;
    int s = v[0] + v[1] + v[2] + v[3];
    sh[t] = s;
    __syncthreads();
    for (int off = 1; off < 256; off <<= 1) {
        int x = (t >= off) ? sh[t - off] : 0;
        __syncthreads();
        sh[t] += x;
        __syncthreads();
    }
    if (t == 255) bsum[blockIdx.x] = sh[255];
    int run = sh[t] - s;
#pragma unroll
    for (int j = 0; j < 4; j++) {
        if (base + j < NN) offs[base + j] = run;
        run += v[j];
    }
}

__global__ __launch_bounds__(128) void k_scan2(const int* __restrict__ bsum, int* __restrict__ bscan, int nb) {
    __shared__ int sh[128];
    int t = threadIdx.x;
    int v = (t < nb) ? bsum[t] : 0;
    sh[t] = v;
    __syncthreads();
    for (int off = 1; off < 128; off <<= 1) {
        int x = (t >= off) ? sh[t - off] : 0;
        __syncthreads();
        sh[t] += x;
        __syncthreads();
    }
    if (t < nb) bscan[t] = sh[t] - v;
}

__global__ __launch_bounds__(256) void k_scan3(const int* __restrict__ cnt, int* __restrict__ offs,
                                               const int* __restrict__ bscan, float* __restrict__ dinv) {
    int i = blockIdx.x * 256 + threadIdx.x;
    if (i >= NN) return;
    int o = offs[i] + bscan[i >> 10];
    offs[i] = o;
    dinv[i] = rsqrtf((float)(cnt[i] + 1));  // +1 self-loop
    if (i == 0) offs[NN] = NE;
}

// ============ bucket bases, padded to multiples of 8 records ============
__global__ __launch_bounds__(256) void k_bscan(const int* __restrict__ offs,
                                               int* __restrict__ pbase, int* __restrict__ pcursor) {
    __shared__ int sh[256];
    int t = threadIdx.x;
    int c[7];
    int s = 0;
#pragma unroll
    for (int j = 0; j < 7; j++) {
        int b = t * 7 + j;
        int v = 0;
        if (b < NBUCK) {
            int n0 = b << 6;
            int n1 = (b + 1) << 6;
            if (n1 > NN) n1 = NN;
            v = (offs[n1] - offs[n0] + 7) & ~7;  // pad to x8
        }
        c[j] = v;
        s += v;
    }
    sh[t] = s;
    __syncthreads();
    for (int off = 1; off < 256; off <<= 1) {
        int x = (t >= off) ? sh[t - off] : 0;
        __syncthreads();
        sh[t] += x;
        __syncthreads();
    }
    int run = sh[t] - s;
#pragma unroll
    for (int j = 0; j < 7; j++) {
        int b = t * 7 + j;
        if (b < NBUCK) { pbase[b] = run; pcursor[b] = run; }
        run += c[j];
    }
    if (t == 255) pbase[NBUCK] = run;
}

// ============ binning: es[pos] = src | (dstLocal << 17), per-bucket append ============
__global__ __launch_bounds__(256) void k_bin(const int* __restrict__ src, const int* __restrict__ dst,
                                             int* __restrict__ pcursor, int* __restrict__ es) {
    int stride = gridDim.x * 256;
    for (int e = blockIdx.x * 256 + threadIdx.x; e < NE; e += stride) {
        int s = src[e], d = dst[e];
        int pos = atomicAdd(&pcursor[d >> 6], 1);
        es[pos] = s | ((d & 63) << 17);
    }
}

// ============ GEMM: out[M][64] = (X[M][K] @ W[K][64]) * dinv[row] ============
template <int K>
__global__ __launch_bounds__(256) void k_gemm(const float* __restrict__ X,
                                              const float* __restrict__ W,
                                              const float* __restrict__ dinv,
                                              float* __restrict__ out, int M) {
    __shared__ float xs[128 * 68];
    __shared__ float ws[64 * 64];
    const int t = threadIdx.x;
    const int row0 = blockIdx.x * 128;
    const int rg = t >> 3;
    const int f0 = (t & 7) * 8;

    float acc[4][8];
#pragma unroll
    for (int j = 0; j < 4; j++)
#pragma unroll
        for (int c = 0; c < 8; c++) acc[j][c] = 0.0f;

    for (int kc = 0; kc < K; kc += 64) {
        __syncthreads();
        const float4* Wg = (const float4*)(W + (size_t)kc * 64);
        float4* ws4 = (float4*)ws;
#pragma unroll
        for (int i = 0; i < 4; i++) ws4[t + i * 256] = Wg[t + i * 256];
#pragma unroll
        for (int p = 0; p < 8; p++) {
            int rr = p * 16 + (t >> 4);
            int c4 = (t & 15) * 4;
            int row = row0 + rr;
            float4 v = make_float4(0.f, 0.f, 0.f, 0.f);
            if (row < M) v = *(const float4*)(X + (size_t)row * K + kc + c4);
            *(float4*)(&xs[rr * 68 + c4]) = v;
        }
        __syncthreads();

        for (int kk = 0; kk < 64; kk += 4) {
            float4 xv[4];
#pragma unroll
            for (int j = 0; j < 4; j++)
                xv[j] = *(const float4*)(&xs[(rg + 32 * j) * 68 + kk]);
#pragma unroll
            for (int kki = 0; kki < 4; kki++) {
                float4 w0 = *(const float4*)(&ws[(kk + kki) * 64 + f0]);
                float4 w1 = *(const float4*)(&ws[(kk + kki) * 64 + f0 + 4]);
#pragma unroll
                for (int j = 0; j < 4; j++) {
                    float a = (&xv[j].x)[kki];
                    acc[j][0] = fmaf(a, w0.x, acc[j][0]);
                    acc[j][1] = fmaf(a, w0.y, acc[j][1]);
                    acc[j][2] = fmaf(a, w0.z, acc[j][2]);
                    acc[j][3] = fmaf(a, w0.w, acc[j][3]);
                    acc[j][4] = fmaf(a, w1.x, acc[j][4]);
                    acc[j][5] = fmaf(a, w1.y, acc[j][5]);
                    acc[j][6] = fmaf(a, w1.z, acc[j][6]);
                    acc[j][7] = fmaf(a, w1.w, acc[j][7]);
                }
            }
        }
    }

#pragma unroll
    for (int j = 0; j < 4; j++) {
        int row = row0 + rg + 32 * j;
        if (row < M) {
            float di = dinv[row];
            float4* o = (float4*)(out + (size_t)row * 64 + f0);
            o[0] = make_float4(acc[j][0] * di, acc[j][1] * di, acc[j][2] * di, acc[j][3] * di);
            o[1] = make_float4(acc[j][4] * di, acc[j][5] * di, acc[j][6] * di, acc[j][7] * di);
        }
    }
}

// ============ bucket aggregation: LDS acc per 64-node bucket, fused epilogue ============
// out[d] = relu( bn( dinv[d]*(sum_{e->d} hp[s] + hp[d]) + bias ) )
__global__ __launch_bounds__(256) void k_aggB(const float* __restrict__ hp,
                                              const int* __restrict__ es,
                                              const int* __restrict__ pbase,
                                              const float* __restrict__ dinv,
                                              const float* __restrict__ bias,
                                              const float* __restrict__ gam,
                                              const float* __restrict__ bet,
                                              const float* __restrict__ rm,
                                              const float* __restrict__ rv,
                                              float* __restrict__ out) {
    __shared__ float acc[65 * 64];  // row 64 = dummy sink for sentinel pads
    const int t = threadIdx.x;
    const int lane = t & 63;
    const int wid = __builtin_amdgcn_readfirstlane(t >> 6);
    const int b = blockIdx.x;

    // zero LDS (65*64 floats = 4160 float4s... 1040 float4; 256 thr -> 5 each, bounds-checked)
    {
        float4* a4 = (float4*)acc;
#pragma unroll
        for (int i = 0; i < 5; i++) {
            int idx = t + 256 * i;
            if (idx < 65 * 16) a4[idx] = make_float4(0.f, 0.f, 0.f, 0.f);
        }
    }

    const int beg = __builtin_amdgcn_readfirstlane(pbase[b]);
    const int end = __builtin_amdgcn_readfirstlane(pbase[b + 1]);

    // BN constants per lane (independent of edge loop)
    const float sc = gam[lane] * rsqrtf(rv[lane] + BN_EPS);
    const float sh0 = bet[lane] - rm[lane] * sc;

    __syncthreads();

    const int ng = (end - beg) >> 3;  // padded to x8, no tail
    for (int g = wid; g < ng; g += 4) {
        int base = beg + g * 8;
        int4 ra = *(const int4*)(es + base);
        int4 rb = *(const int4*)(es + base + 4);
        int r[8] = {ra.x, ra.y, ra.z, ra.w, rb.x, rb.y, rb.z, rb.w};
        float v[8];
        int dl[8];
#pragma unroll
        for (int j = 0; j < 8; j++) {
            bool ok = r[j] >= 0;
            int s = ok ? (r[j] & 0x1FFFF) : 0;
            dl[j] = ok ? (r[j] >> 17) : 64;      // sentinel -> dummy row
            v[j] = hp[(size_t)s * 64 + lane];    // harmless load for sentinel (s=0)
        }
#pragma unroll
        for (int j = 0; j < 8; j++)
            atomicAdd(&acc[dl[j] * 64 + lane], v[j]);
    }

    __syncthreads();

    // epilogue: self-term + dinv scale + bias/BN/ReLU, one write per row
#pragma unroll
    for (int i = wid; i < 64; i += 4) {
        int node = (b << 6) + i;
        if (node < NN) {
            float di = dinv[node];
            float tot = acc[i * 64 + lane] + hp[(size_t)node * 64 + lane];
            float val = tot * di + bias[lane];
            float y = val * sc + sh0;
            out[(size_t)node * 64 + lane] = fmaxf(y, 0.0f);
        }
    }
}

// ================= segmented mean-pool (batch sorted) =================
__global__ __launch_bounds__(256) void k_pool(const float* __restrict__ h,
                                              const int* __restrict__ batch,
                                              float* __restrict__ pool, float* __restrict__ cnt) {
    int lane = threadIdx.x & 63;
    int wid = (blockIdx.x * 256 + threadIdx.x) >> 6;
    int base = wid * 64;
    if (base >= NN) return;
    int nl = base + lane;
    int bi = (nl < NN) ? batch[nl] : -1;
    int lim = min(64, NN - base);
    float acc = 0.0f;
    int curg = __shfl(bi, 0);
    int runlen = 0;
    for (int i = 0; i < lim; i++) {
        int g = __shfl(bi, i);
        if (g != curg) {
            atomicAdd(&pool[curg * 64 + lane], acc);
            if (lane == 0) atomicAdd(&cnt[curg], (float)runlen);
            acc = 0.0f; runlen = 0; curg = g;
        }
        acc += h[(size_t)(base + i) * 64 + lane];
        runlen++;
    }
    atomicAdd(&pool[curg * 64 + lane], acc);
    if (lane == 0) atomicAdd(&cnt[curg], (float)runlen);
}

__global__ __launch_bounds__(64) void k_classify(const float* __restrict__ pool,
                                                 const float* __restrict__ cnt,
                                                 const float* __restrict__ Wc,
                                                 const float* __restrict__ bc,
                                                 float* __restrict__ out) {
    int g = blockIdx.x;
    int lane = threadIdx.x;
    float inv = 1.0f / fmaxf(cnt[g], 1.0f);
    float p = pool[g * 64 + lane] * inv;
    float s0 = p * Wc[lane * 3 + 0];
    float s1 = p * Wc[lane * 3 + 1];
    float s2 = p * Wc[lane * 3 + 2];
    for (int o = 32; o > 0; o >>= 1) {
        s0 += __shfl_xor(s0, o);
        s1 += __shfl_xor(s1, o);
        s2 += __shfl_xor(s2, o);
    }
    if (lane == 0) {
        out[g * 3 + 0] = s0 + bc[0];
        out[g * 3 + 1] = s1 + bc[1];
        out[g * 3 + 2] = s2 + bc[2];
    }
}

extern "C" void kernel_launch(void* const* d_in, const int* in_sizes, int n_in,
                              void* d_out, int out_size, void* d_ws, size_t ws_size,
                              hipStream_t stream) {
    const float* x   = (const float*)d_in[0];
    const float* W1  = (const float*)d_in[1];
    const float* b1  = (const float*)d_in[2];
    const float* g1  = (const float*)d_in[3];
    const float* bt1 = (const float*)d_in[4];
    const float* rm1 = (const float*)d_in[5];
    const float* rv1 = (const float*)d_in[6];
    const float* W2  = (const float*)d_in[7];
    const float* b2  = (const float*)d_in[8];
    const float* g2  = (const float*)d_in[9];
    const float* bt2 = (const float*)d_in[10];
    const float* rm2 = (const float*)d_in[11];
    const float* rv2 = (const float*)d_in[12];
    const float* Wc  = (const float*)d_in[13];
    const float* bc  = (const float*)d_in[14];
    const int* ei    = (const int*)d_in[15];
    const int* batch = (const int*)d_in[16];
    const int* srcp = ei;
    const int* dstp = ei + NE;

    char* ws = (char*)d_ws;
    int*   cnt     = (int*)(ws);                    // NN
    int*   offs    = (int*)(ws + 400064);           // NN+1
    int*   bsum    = (int*)(ws + 800640);           // 128
    int*   bscan   = (int*)(ws + 801152);           // 128
    float* dinv    = (float*)(ws + 801664);         // NN
    int*   pbase   = (int*)(ws + 1201664);          // NBUCK+1
    int*   pcursor = (int*)(ws + 1208128);          // NBUCK
    int*   es      = (int*)(ws + 1214592);          // ES_CAP ints (~12.85 MB)
    float* bufA    = (float*)(ws + 14064640);       // NN*64
    float* bufB    = (float*)(ws + 39664640);       // NN*64
    float* pool    = (float*)(ws + 65264640);       // 512*64
    float* gcnt    = (float*)(ws + 65395712);       // 512

    // ---- degree + scans + bucket bases ----
    hipMemsetAsync(cnt, 0, (size_t)NN * 4, stream);
    k_hist<<<2048, 256, 0, stream>>>(dstp, cnt);
    int nb = (NN + 1023) / 1024;  // 98
    k_scan1<<<nb, 256, 0, stream>>>(cnt, offs, bsum);
    k_scan2<<<1, 128, 0, stream>>>(bsum, bscan, nb);
    k_scan3<<<(NN + 255) / 256, 256, 0, stream>>>(cnt, offs, bscan, dinv);
    k_bscan<<<1, 256, 0, stream>>>(offs, pbase, pcursor);

    // ---- binning (sentinel-padded) ----
    hipMemsetAsync(es, 0xFF, (size_t)ES_CAP * 4, stream);
    k_bin<<<2048, 256, 0, stream>>>(srcp, dstp, pcursor, es);

    // ---- layer 1 ----
    k_gemm<128><<<(NN + 127) / 128, 256, 0, stream>>>(x, W1, dinv, bufA, NN);
    k_aggB<<<NBUCK, 256, 0, stream>>>(bufA, es, pbase, dinv, b1, g1, bt1, rm1, rv1, bufB);

    // ---- layer 2 ----
    k_gemm<64><<<(NN + 127) / 128, 256, 0, stream>>>(bufB, W2, dinv, bufA, NN);
    k_aggB<<<NBUCK, 256, 0, stream>>>(bufA, es, pbase, dinv, b2, g2, bt2, rm2, rv2, bufB);

    // ---- pool + classify ----
    hipMemsetAsync(pool, 0, 512 * 64 * 4 + 512 * 4, stream);
    k_pool<<<(((NN + 63) / 64) + 3) / 4, 256, 0, stream>>>(bufB, batch, pool, gcnt);
    k_classify<<<NG, 64, 0, stream>>>(pool, gcnt, Wc, bc, (float*)d_out);
}

// Round 4
// 602.588 us; speedup vs baseline: 5.2757x; 5.2757x over previous
//
#include <hip/hip_runtime.h>

#define NN 100000
#define NE 3200000
#define NG 512
#define NCB 782           // coarse buckets of 128 nodes: ceil(100000/128)
#define BN_EPS 1e-5f

// ================= coarse histogram (LDS-privatized) =================
__global__ __launch_bounds__(256) void k_chist(const int* __restrict__ dst, int* __restrict__ ccount) {
    __shared__ int h[NCB];
    int t = threadIdx.x;
    for (int i = t; i < NCB; i += 256) h[i] = 0;
    __syncthreads();
    int stride = gridDim.x * 256;
    for (int e = blockIdx.x * 256 + t; e < NE; e += stride)
        atomicAdd(&h[dst[e] >> 7], 1);
    __syncthreads();
    for (int i = t; i < NCB; i += 256)
        if (h[i]) atomicAdd(&ccount[i], h[i]);
}

// ========== scan coarse counts -> cbase (coarse regions), fbase (padded fine regions), gcur ==========
__global__ __launch_bounds__(256) void k_cscan(const int* __restrict__ ccount, int* __restrict__ cbase,
                                               int* __restrict__ fbase, int* __restrict__ gcur) {
    __shared__ int sh[256], sh2[256];
    int t = threadIdx.x;
    int v[4], w[4];
    int s = 0, s2 = 0;
#pragma unroll
    for (int j = 0; j < 4; j++) {
        int idx = t * 4 + j;
        int c = (idx < NCB) ? ccount[idx] : 0;
        v[j] = c;
        w[j] = (idx < NCB) ? ((c + 387) & ~3) : 0;  // room for <=3 pad per node * 128 nodes, x4 aligned
        s += v[j]; s2 += w[j];
    }
    sh[t] = s; sh2[t] = s2;
    __syncthreads();
    for (int off = 1; off < 256; off <<= 1) {
        int x = (t >= off) ? sh[t - off] : 0;
        int x2 = (t >= off) ? sh2[t - off] : 0;
        __syncthreads();
        sh[t] += x; sh2[t] += x2;
        __syncthreads();
    }
    int run = sh[t] - s, run2 = sh2[t] - s2;
#pragma unroll
    for (int j = 0; j < 4; j++) {
        int idx = t * 4 + j;
        if (idx < NCB) { cbase[idx] = run; gcur[idx] = run; fbase[idx] = run2; }
        run += v[j]; run2 += w[j];
    }
    if (t == 255) cbase[NCB] = run;  // == NE
}

// ========== pass 1: coarse binning, block-local LDS counts + bulk reservations ==========
#define P1_CHUNK 4096
__global__ __launch_bounds__(256) void k_p1(const int* __restrict__ src, const int* __restrict__ dst,
                                            int* __restrict__ gcur, int* __restrict__ esc) {
    __shared__ int ccur[NCB];
    int t = threadIdx.x;
    int e0 = blockIdx.x * P1_CHUNK;
    for (int i = t; i < NCB; i += 256) ccur[i] = 0;
    __syncthreads();
    int n = NE - e0; if (n > P1_CHUNK) n = P1_CHUNK;
    int d[16];
#pragma unroll
    for (int j = 0; j < 16; j++) {
        int idx = t + j * 256;
        d[j] = (idx < n) ? dst[e0 + idx] : -1;
        if (d[j] >= 0) atomicAdd(&ccur[d[j] >> 7], 1);
    }
    __syncthreads();
    for (int i = t; i < NCB; i += 256) {
        int c = ccur[i];
        ccur[i] = (c > 0) ? atomicAdd(&gcur[i], c) : 0;  // reserve once per (block,bucket)
    }
    __syncthreads();
#pragma unroll
    for (int j = 0; j < 16; j++) {
        if (d[j] >= 0) {
            int idx = t + j * 256;
            int s = src[e0 + idx];
            int pos = atomicAdd(&ccur[d[j] >> 7], 1);
            esc[pos] = s | ((d[j] & 127) << 17);  // 17b src | 7b dstLocal
        }
    }
}

// ========== pass 2: fine per-node CSR within each coarse bucket (all LDS), emits offs/cntp/dinv ==========
__global__ __launch_bounds__(256) void k_p2(const int* __restrict__ esc, const int* __restrict__ cbase,
                                            const int* __restrict__ fbase, int* __restrict__ esf,
                                            int* __restrict__ offs, int* __restrict__ cntp,
                                            float* __restrict__ dinv) {
    __shared__ int lcnt[128], loff[128], lcur[128];
    int t = threadIdx.x, b = blockIdx.x;
    int c0 = cbase[b], c1 = cbase[b + 1];
    if (t < 128) lcnt[t] = 0;
    __syncthreads();
    for (int i = c0 + t; i < c1; i += 256) atomicAdd(&lcnt[esc[i] >> 17], 1);
    __syncthreads();
    int p = 0, cnt = 0;
    if (t < 128) { cnt = lcnt[t]; p = (cnt + 3) & ~3; loff[t] = p; }
    __syncthreads();
    for (int off = 1; off < 128; off <<= 1) {
        int x = (t >= off && t < 128) ? loff[t - off] : 0;
        __syncthreads();
        if (t < 128) loff[t] += x;
        __syncthreads();
    }
    int fb = fbase[b];
    int node = (b << 7) + t;
    if (t < 128) {
        int o = fb + loff[t] - p;  // exclusive padded offset
        lcur[t] = o;
        if (node < NN) {
            offs[node] = o;
            cntp[node] = p;
            dinv[node] = rsqrtf((float)(cnt + 1));  // +1 self-loop
            for (int q = cnt; q < p; q++) esf[o + q] = NN;  // sentinel pads -> zero row
        }
    }
    __syncthreads();
    for (int i = c0 + t; i < c1; i += 256) {
        int rec = esc[i];
        int pos = atomicAdd(&lcur[rec >> 17], 1);
        esf[pos] = rec & 0x1FFFF;
    }
}

// ============ GEMM: out[M][64] = (X[M][K] @ W[K][64]) * dinv[row] ============
template <int K>
__global__ __launch_bounds__(256) void k_gemm(const float* __restrict__ X,
                                              const float* __restrict__ W,
                                              const float* __restrict__ dinv,
                                              float* __restrict__ out, int M) {
    __shared__ float xs[128 * 68];
    __shared__ float ws[64 * 64];
    const int t = threadIdx.x;
    const int row0 = blockIdx.x * 128;
    const int rg = t >> 3;
    const int f0 = (t & 7) * 8;

    float acc[4][8];
#pragma unroll
    for (int j = 0; j < 4; j++)
#pragma unroll
        for (int c = 0; c < 8; c++) acc[j][c] = 0.0f;

    for (int kc = 0; kc < K; kc += 64) {
        __syncthreads();
        const float4* Wg = (const float4*)(W + (size_t)kc * 64);
        float4* ws4 = (float4*)ws;
#pragma unroll
        for (int i = 0; i < 4; i++) ws4[t + i * 256] = Wg[t + i * 256];
#pragma unroll
        for (int p = 0; p < 8; p++) {
            int rr = p * 16 + (t >> 4);
            int c4 = (t & 15) * 4;
            int row = row0 + rr;
            float4 v = make_float4(0.f, 0.f, 0.f, 0.f);
            if (row < M) v = *(const float4*)(X + (size_t)row * K + kc + c4);
            *(float4*)(&xs[rr * 68 + c4]) = v;
        }
        __syncthreads();

        for (int kk = 0; kk < 64; kk += 4) {
            float4 xv[4];
#pragma unroll
            for (int j = 0; j < 4; j++)
                xv[j] = *(const float4*)(&xs[(rg + 32 * j) * 68 + kk]);
#pragma unroll
            for (int kki = 0; kki < 4; kki++) {
                float4 w0 = *(const float4*)(&ws[(kk + kki) * 64 + f0]);
                float4 w1 = *(const float4*)(&ws[(kk + kki) * 64 + f0 + 4]);
#pragma unroll
                for (int j = 0; j < 4; j++) {
                    float a = (&xv[j].x)[kki];
                    acc[j][0] = fmaf(a, w0.x, acc[j][0]);
                    acc[j][1] = fmaf(a, w0.y, acc[j][1]);
                    acc[j][2] = fmaf(a, w0.z, acc[j][2]);
                    acc[j][3] = fmaf(a, w0.w, acc[j][3]);
                    acc[j][4] = fmaf(a, w1.x, acc[j][4]);
                    acc[j][5] = fmaf(a, w1.y, acc[j][5]);
                    acc[j][6] = fmaf(a, w1.z, acc[j][6]);
                    acc[j][7] = fmaf(a, w1.w, acc[j][7]);
                }
            }
        }
    }

#pragma unroll
    for (int j = 0; j < 4; j++) {
        int row = row0 + rg + 32 * j;
        if (row < M) {
            float di = dinv[row];
            float4* o = (float4*)(out + (size_t)row * 64 + f0);
            o[0] = make_float4(acc[j][0] * di, acc[j][1] * di, acc[j][2] * di, acc[j][3] * di);
            o[1] = make_float4(acc[j][4] * di, acc[j][5] * di, acc[j][6] * di, acc[j][7] * di);
        }
    }
}

// ============ wave-per-node CSR aggregation, 4B records, fused epilogue ============
// out[d] = relu( bn( dinv[d]*(sum hp[s] + hp[d]) + bias ) ),  hp = (XW)*dinv pre-scaled
__global__ __launch_bounds__(256) void k_agg(const float* __restrict__ hp,
                                             const int* __restrict__ esf,
                                             const int* __restrict__ offs,
                                             const int* __restrict__ cntp,
                                             const float* __restrict__ dinv,
                                             const float* __restrict__ bias,
                                             const float* __restrict__ gam,
                                             const float* __restrict__ bet,
                                             const float* __restrict__ rm,
                                             const float* __restrict__ rv,
                                             float* __restrict__ out) {
    const int lane = threadIdx.x & 63;
    const int node = (blockIdx.x * 256 + threadIdx.x) >> 6;
    if (node >= NN) return;
    const int beg = offs[node];
    const int mp = cntp[node];  // multiple of 4 (sentinel-padded)
    float acc = 0.0f;
    for (int c = 0; c < mp; c += 64) {
        int m = mp - c;
        if (m > 64) m = 64;
        int rec = (lane < m) ? esf[beg + c + lane] : NN;
        for (int j = 0; j < m; j += 4) {
#pragma unroll
            for (int u = 0; u < 4; u++) {
                int s = __shfl(rec, j + u);
                acc += hp[(size_t)s * 64 + lane];  // s==NN -> zero row
            }
        }
    }
    float di = dinv[node];
    float val = (acc + hp[(size_t)node * 64 + lane]) * di + bias[lane];
    float sc = gam[lane] * rsqrtf(rv[lane] + BN_EPS);
    float y = (val - rm[lane]) * sc + bet[lane];
    out[(size_t)node * 64 + lane] = fmaxf(y, 0.0f);
}

// ================= segmented mean-pool (batch sorted) =================
__global__ __launch_bounds__(256) void k_pool(const float* __restrict__ h,
                                              const int* __restrict__ batch,
                                              float* __restrict__ pool, float* __restrict__ cnt) {
    int lane = threadIdx.x & 63;
    int wid = (blockIdx.x * 256 + threadIdx.x) >> 6;
    int base = wid * 64;
    if (base >= NN) return;
    int nl = base + lane;
    int bi = (nl < NN) ? batch[nl] : -1;
    int lim = min(64, NN - base);
    float acc = 0.0f;
    int curg = __shfl(bi, 0);
    int runlen = 0;
    for (int i = 0; i < lim; i++) {
        int g = __shfl(bi, i);
        if (g != curg) {
            atomicAdd(&pool[curg * 64 + lane], acc);
            if (lane == 0) atomicAdd(&cnt[curg], (float)runlen);
            acc = 0.0f; runlen = 0; curg = g;
        }
        acc += h[(size_t)(base + i) * 64 + lane];
        runlen++;
    }
    atomicAdd(&pool[curg * 64 + lane], acc);
    if (lane == 0) atomicAdd(&cnt[curg], (float)runlen);
}

__global__ __launch_bounds__(64) void k_classify(const float* __restrict__ pool,
                                                 const float* __restrict__ cnt,
                                                 const float* __restrict__ Wc,
                                                 const float* __restrict__ bc,
                                                 float* __restrict__ out) {
    int g = blockIdx.x;
    int lane = threadIdx.x;
    float inv = 1.0f / fmaxf(cnt[g], 1.0f);
    float p = pool[g * 64 + lane] * inv;
    float s0 = p * Wc[lane * 3 + 0];
    float s1 = p * Wc[lane * 3 + 1];
    float s2 = p * Wc[lane * 3 + 2];
    for (int o = 32; o > 0; o >>= 1) {
        s0 += __shfl_xor(s0, o);
        s1 += __shfl_xor(s1, o);
        s2 += __shfl_xor(s2, o);
    }
    if (lane == 0) {
        out[g * 3 + 0] = s0 + bc[0];
        out[g * 3 + 1] = s1 + bc[1];
        out[g * 3 + 2] = s2 + bc[2];
    }
}

extern "C" void kernel_launch(void* const* d_in, const int* in_sizes, int n_in,
                              void* d_out, int out_size, void* d_ws, size_t ws_size,
                              hipStream_t stream) {
    const float* x   = (const float*)d_in[0];
    const float* W1  = (const float*)d_in[1];
    const float* b1  = (const float*)d_in[2];
    const float* g1  = (const float*)d_in[3];
    const float* bt1 = (const float*)d_in[4];
    const float* rm1 = (const float*)d_in[5];
    const float* rv1 = (const float*)d_in[6];
    const float* W2  = (const float*)d_in[7];
    const float* b2  = (const float*)d_in[8];
    const float* g2  = (const float*)d_in[9];
    const float* bt2 = (const float*)d_in[10];
    const float* rm2 = (const float*)d_in[11];
    const float* rv2 = (const float*)d_in[12];
    const float* Wc  = (const float*)d_in[13];
    const float* bc  = (const float*)d_in[14];
    const int* ei    = (const int*)d_in[15];
    const int* batch = (const int*)d_in[16];
    const int* srcp = ei;
    const int* dstp = ei + NE;

    char* ws = (char*)d_ws;
    int*   ccount = (int*)(ws);                 // NCB
    int*   cbase  = (int*)(ws + 4096);          // NCB+1
    int*   fbase  = (int*)(ws + 8192);          // NCB
    int*   gcur   = (int*)(ws + 12288);         // NCB
    int*   offs   = (int*)(ws + 16384);         // NN
    int*   cntp   = (int*)(ws + 416768);        // NN
    float* dinv   = (float*)(ws + 816768);      // NN
    int*   esf    = (int*)(ws + 1216768);       // NE + 388*NCB ints (~14 MB)
    float* bufA   = (float*)(ws + 15230432);    // (NN+1)*64 floats (row NN = zero row)
    float* bufB   = (float*)(ws + 40830688);    // NN*64 floats
    int*   esc    = (int*)(ws + 40830688);      // NE ints — overlaps bufB (dead before agg1 writes bufB)
    float* pool   = (float*)(ws + 66430688);    // 512*64
    float* gcnt   = (float*)(ws + 66561760);    // 512

    // ---- init ----
    hipMemsetAsync(ccount, 0, NCB * 4, stream);
    hipMemsetAsync(bufA + (size_t)NN * 64, 0, 64 * 4, stream);   // sentinel zero row
    hipMemsetAsync(pool, 0, 512 * 64 * 4 + 512 * 4, stream);     // pool + gcnt contiguous

    // ---- CSR build: coarse hist -> scan -> coarse bin -> fine bin (emits offs/cntp/dinv) ----
    k_chist<<<512, 256, 0, stream>>>(dstp, ccount);
    k_cscan<<<1, 256, 0, stream>>>(ccount, cbase, fbase, gcur);
    k_p1<<<(NE + P1_CHUNK - 1) / P1_CHUNK, 256, 0, stream>>>(srcp, dstp, gcur, esc);
    k_p2<<<NCB, 256, 0, stream>>>(esc, cbase, fbase, esf, offs, cntp, dinv);

    // ---- layer 1 ----
    k_gemm<128><<<(NN + 127) / 128, 256, 0, stream>>>(x, W1, dinv, bufA, NN);
    k_agg<<<(NN * 64 + 255) / 256, 256, 0, stream>>>(bufA, esf, offs, cntp, dinv, b1, g1, bt1, rm1, rv1, bufB);

    // ---- layer 2 ----
    k_gemm<64><<<(NN + 127) / 128, 256, 0, stream>>>(bufB, W2, dinv, bufA, NN);
    k_agg<<<(NN * 64 + 255) / 256, 256, 0, stream>>>(bufA, esf, offs, cntp, dinv, b2, g2, bt2, rm2, rv2, bufB);

    // ---- pool + classify ----
    k_pool<<<(((NN + 63) / 64) + 3) / 4, 256, 0, stream>>>(bufB, batch, pool, gcnt);
    k_classify<<<NG, 64, 0, stream>>>(pool, gcnt, Wc, bc, (float*)d_out);
}

// Round 5
// 474.130 us; speedup vs baseline: 6.7051x; 1.2709x over previous
//
#include <hip/hip_runtime.h>

#define NN 100000
#define NE 3200000
#define NG 512
#define NCB 782           // coarse buckets of 128 nodes: ceil(100000/128)
#define BN_EPS 1e-5f

typedef unsigned short u16;
typedef unsigned int u32;

__device__ __forceinline__ u16 f2bf(float f) {
    u32 u = __float_as_uint(f);
    u += 0x7FFF + ((u >> 16) & 1);  // RNE
    return (u16)(u >> 16);
}
__device__ __forceinline__ float bf2f(u16 u) {
    return __uint_as_float(((u32)u) << 16);
}

// ================= coarse histogram (LDS-privatized) =================
__global__ __launch_bounds__(256) void k_chist(const int* __restrict__ dst, int* __restrict__ ccount) {
    __shared__ int h[NCB];
    int t = threadIdx.x;
    for (int i = t; i < NCB; i += 256) h[i] = 0;
    __syncthreads();
    int stride = gridDim.x * 256;
    for (int e = blockIdx.x * 256 + t; e < NE; e += stride)
        atomicAdd(&h[dst[e] >> 7], 1);
    __syncthreads();
    for (int i = t; i < NCB; i += 256)
        if (h[i]) atomicAdd(&ccount[i], h[i]);
}

// ========== scan coarse counts -> cbase, padded fine bases, global cursors ==========
__global__ __launch_bounds__(256) void k_cscan(const int* __restrict__ ccount, int* __restrict__ cbase,
                                               int* __restrict__ fbase, int* __restrict__ gcur) {
    __shared__ int sh[256], sh2[256];
    int t = threadIdx.x;
    int v[4], w[4];
    int s = 0, s2 = 0;
#pragma unroll
    for (int j = 0; j < 4; j++) {
        int idx = t * 4 + j;
        int c = (idx < NCB) ? ccount[idx] : 0;
        v[j] = c;
        w[j] = (idx < NCB) ? ((c + 387) & ~3) : 0;
        s += v[j]; s2 += w[j];
    }
    sh[t] = s; sh2[t] = s2;
    __syncthreads();
    for (int off = 1; off < 256; off <<= 1) {
        int x = (t >= off) ? sh[t - off] : 0;
        int x2 = (t >= off) ? sh2[t - off] : 0;
        __syncthreads();
        sh[t] += x; sh2[t] += x2;
        __syncthreads();
    }
    int run = sh[t] - s, run2 = sh2[t] - s2;
#pragma unroll
    for (int j = 0; j < 4; j++) {
        int idx = t * 4 + j;
        if (idx < NCB) { cbase[idx] = run; gcur[idx] = run; fbase[idx] = run2; }
        run += v[j]; run2 += w[j];
    }
    if (t == 255) cbase[NCB] = run;  // == NE
}

// ========== pass 1: coarse binning, block-local LDS counts + bulk reservations ==========
#define P1_CHUNK 8192
__global__ __launch_bounds__(256) void k_p1(const int* __restrict__ src, const int* __restrict__ dst,
                                            int* __restrict__ gcur, int* __restrict__ esc) {
    __shared__ int ccur[NCB];
    int t = threadIdx.x;
    int e0 = blockIdx.x * P1_CHUNK;
    for (int i = t; i < NCB; i += 256) ccur[i] = 0;
    __syncthreads();
    int n = NE - e0; if (n > P1_CHUNK) n = P1_CHUNK;
    int d[32];
#pragma unroll
    for (int j = 0; j < 32; j++) {
        int idx = t + j * 256;
        d[j] = (idx < n) ? dst[e0 + idx] : -1;
        if (d[j] >= 0) atomicAdd(&ccur[d[j] >> 7], 1);
    }
    __syncthreads();
    for (int i = t; i < NCB; i += 256) {
        int c = ccur[i];
        ccur[i] = (c > 0) ? atomicAdd(&gcur[i], c) : 0;  // one reservation per (block,bucket)
    }
    __syncthreads();
#pragma unroll
    for (int j = 0; j < 32; j++) {
        if (d[j] >= 0) {
            int idx = t + j * 256;
            int s = src[e0 + idx];
            int pos = atomicAdd(&ccur[d[j] >> 7], 1);
            esc[pos] = s | ((d[j] & 127) << 17);  // 17b src | 7b dstLocal
        }
    }
}

// ========== pass 2: fine per-node CSR within each coarse bucket; emits offs/cntp/dinv ==========
__global__ __launch_bounds__(256) void k_p2(const int* __restrict__ esc, const int* __restrict__ cbase,
                                            const int* __restrict__ fbase, int* __restrict__ esf,
                                            int* __restrict__ offs, int* __restrict__ cntp,
                                            float* __restrict__ dinv) {
    __shared__ int lcnt[128], loff[128], lcur[128];
    int t = threadIdx.x, b = blockIdx.x;
    int c0 = cbase[b], c1 = cbase[b + 1];
    if (t < 128) lcnt[t] = 0;
    __syncthreads();
    for (int i = c0 + t; i < c1; i += 256) atomicAdd(&lcnt[esc[i] >> 17], 1);
    __syncthreads();
    int p = 0, cnt = 0;
    if (t < 128) { cnt = lcnt[t]; p = (cnt + 3) & ~3; loff[t] = p; }
    __syncthreads();
    for (int off = 1; off < 128; off <<= 1) {
        int x = (t >= off && t < 128) ? loff[t - off] : 0;
        __syncthreads();
        if (t < 128) loff[t] += x;
        __syncthreads();
    }
    int fb = fbase[b];
    int node = (b << 7) + t;
    if (t < 128) {
        int o = fb + loff[t] - p;
        lcur[t] = o;
        if (node < NN) {
            offs[node] = o;
            cntp[node] = p;
            dinv[node] = rsqrtf((float)(cnt + 1));  // +1 self-loop
            for (int q = cnt; q < p; q++) esf[o + q] = NN;  // sentinel -> zero row
        }
    }
    __syncthreads();
    for (int i = c0 + t; i < c1; i += 256) {
        int rec = esc[i];
        int pos = atomicAdd(&lcur[rec >> 17], 1);
        esf[pos] = rec & 0x1FFFF;
    }
}

// ===== GEMM: hp[M][64] = bf16( (X[M][K] @ W[K][64]) * dinv[row] ) =====
template <int K>
__global__ __launch_bounds__(256) void k_gemm(const float* __restrict__ X,
                                              const float* __restrict__ W,
                                              const float* __restrict__ dinv,
                                              u16* __restrict__ hp, int M) {
    __shared__ float xs[128 * 68];
    __shared__ float ws[64 * 64];
    const int t = threadIdx.x;
    const int row0 = blockIdx.x * 128;
    const int rg = t >> 3;
    const int f0 = (t & 7) * 8;

    float acc[4][8];
#pragma unroll
    for (int j = 0; j < 4; j++)
#pragma unroll
        for (int c = 0; c < 8; c++) acc[j][c] = 0.0f;

    for (int kc = 0; kc < K; kc += 64) {
        __syncthreads();
        const float4* Wg = (const float4*)(W + (size_t)kc * 64);
        float4* ws4 = (float4*)ws;
#pragma unroll
        for (int i = 0; i < 4; i++) ws4[t + i * 256] = Wg[t + i * 256];
#pragma unroll
        for (int p = 0; p < 8; p++) {
            int rr = p * 16 + (t >> 4);
            int c4 = (t & 15) * 4;
            int row = row0 + rr;
            float4 v = make_float4(0.f, 0.f, 0.f, 0.f);
            if (row < M) v = *(const float4*)(X + (size_t)row * K + kc + c4);
            *(float4*)(&xs[rr * 68 + c4]) = v;
        }
        __syncthreads();

        for (int kk = 0; kk < 64; kk += 4) {
            float4 xv[4];
#pragma unroll
            for (int j = 0; j < 4; j++)
                xv[j] = *(const float4*)(&xs[(rg + 32 * j) * 68 + kk]);
#pragma unroll
            for (int kki = 0; kki < 4; kki++) {
                float4 w0 = *(const float4*)(&ws[(kk + kki) * 64 + f0]);
                float4 w1 = *(const float4*)(&ws[(kk + kki) * 64 + f0 + 4]);
#pragma unroll
                for (int j = 0; j < 4; j++) {
                    float a = (&xv[j].x)[kki];
                    acc[j][0] = fmaf(a, w0.x, acc[j][0]);
                    acc[j][1] = fmaf(a, w0.y, acc[j][1]);
                    acc[j][2] = fmaf(a, w0.z, acc[j][2]);
                    acc[j][3] = fmaf(a, w0.w, acc[j][3]);
                    acc[j][4] = fmaf(a, w1.x, acc[j][4]);
                    acc[j][5] = fmaf(a, w1.y, acc[j][5]);
                    acc[j][6] = fmaf(a, w1.z, acc[j][6]);
                    acc[j][7] = fmaf(a, w1.w, acc[j][7]);
                }
            }
        }
    }

#pragma unroll
    for (int j = 0; j < 4; j++) {
        int row = row0 + rg + 32 * j;
        if (row < M) {
            float di = dinv[row];
            uint4 pk;
            pk.x = (u32)f2bf(acc[j][0] * di) | ((u32)f2bf(acc[j][1] * di) << 16);
            pk.y = (u32)f2bf(acc[j][2] * di) | ((u32)f2bf(acc[j][3] * di) << 16);
            pk.z = (u32)f2bf(acc[j][4] * di) | ((u32)f2bf(acc[j][5] * di) << 16);
            pk.w = (u32)f2bf(acc[j][6] * di) | ((u32)f2bf(acc[j][7] * di) << 16);
            *(uint4*)(hp + (size_t)row * 64 + f0) = pk;
        }
    }
}

// ===== wave-per-node CSR aggregation over bf16 hp, fp32 accumulate, fused epilogue =====
// out[d] = relu( bn( dinv[d]*(sum hp[s] + hp[d]) + bias ) )
__global__ __launch_bounds__(256) void k_agg(const u16* __restrict__ hp,
                                             const int* __restrict__ esf,
                                             const int* __restrict__ offs,
                                             const int* __restrict__ cntp,
                                             const float* __restrict__ dinv,
                                             const float* __restrict__ bias,
                                             const float* __restrict__ gam,
                                             const float* __restrict__ bet,
                                             const float* __restrict__ rm,
                                             const float* __restrict__ rv,
                                             float* __restrict__ out) {
    const int lane = threadIdx.x & 63;
    const int node = (blockIdx.x * 256 + threadIdx.x) >> 6;
    if (node >= NN) return;
    const int beg = offs[node];
    const int mp = cntp[node];  // multiple of 4 (sentinel-padded)
    float acc = 0.0f;
    for (int c = 0; c < mp; c += 64) {
        int m = mp - c;
        if (m > 64) m = 64;
        int rec = (lane < m) ? esf[beg + c + lane] : NN;
        for (int j = 0; j < m; j += 4) {
#pragma unroll
            for (int u = 0; u < 4; u++) {
                int s = __shfl(rec, j + u);
                acc += bf2f(hp[(size_t)s * 64 + lane]);  // s==NN -> zero row
            }
        }
    }
    float di = dinv[node];
    float val = (acc + bf2f(hp[(size_t)node * 64 + lane])) * di + bias[lane];
    float sc = gam[lane] * rsqrtf(rv[lane] + BN_EPS);
    float y = (val - rm[lane]) * sc + bet[lane];
    out[(size_t)node * 64 + lane] = fmaxf(y, 0.0f);
}

// ================= segmented mean-pool (batch sorted) =================
__global__ __launch_bounds__(256) void k_pool(const float* __restrict__ h,
                                              const int* __restrict__ batch,
                                              float* __restrict__ pool, float* __restrict__ cnt) {
    int lane = threadIdx.x & 63;
    int wid = (blockIdx.x * 256 + threadIdx.x) >> 6;
    int base = wid * 64;
    if (base >= NN) return;
    int nl = base + lane;
    int bi = (nl < NN) ? batch[nl] : -1;
    int lim = min(64, NN - base);
    float acc = 0.0f;
    int curg = __shfl(bi, 0);
    int runlen = 0;
    for (int i = 0; i < lim; i++) {
        int g = __shfl(bi, i);
        if (g != curg) {
            atomicAdd(&pool[curg * 64 + lane], acc);
            if (lane == 0) atomicAdd(&cnt[curg], (float)runlen);
            acc = 0.0f; runlen = 0; curg = g;
        }
        acc += h[(size_t)(base + i) * 64 + lane];
        runlen++;
    }
    atomicAdd(&pool[curg * 64 + lane], acc);
    if (lane == 0) atomicAdd(&cnt[curg], (float)runlen);
}

__global__ __launch_bounds__(64) void k_classify(const float* __restrict__ pool,
                                                 const float* __restrict__ cnt,
                                                 const float* __restrict__ Wc,
                                                 const float* __restrict__ bc,
                                                 float* __restrict__ out) {
    int g = blockIdx.x;
    int lane = threadIdx.x;
    float inv = 1.0f / fmaxf(cnt[g], 1.0f);
    float p = pool[g * 64 + lane] * inv;
    float s0 = p * Wc[lane * 3 + 0];
    float s1 = p * Wc[lane * 3 + 1];
    float s2 = p * Wc[lane * 3 + 2];
    for (int o = 32; o > 0; o >>= 1) {
        s0 += __shfl_xor(s0, o);
        s1 += __shfl_xor(s1, o);
        s2 += __shfl_xor(s2, o);
    }
    if (lane == 0) {
        out[g * 3 + 0] = s0 + bc[0];
        out[g * 3 + 1] = s1 + bc[1];
        out[g * 3 + 2] = s2 + bc[2];
    }
}

extern "C" void kernel_launch(void* const* d_in, const int* in_sizes, int n_in,
                              void* d_out, int out_size, void* d_ws, size_t ws_size,
                              hipStream_t stream) {
    const float* x   = (const float*)d_in[0];
    const float* W1  = (const float*)d_in[1];
    const float* b1  = (const float*)d_in[2];
    const float* g1  = (const float*)d_in[3];
    const float* bt1 = (const float*)d_in[4];
    const float* rm1 = (const float*)d_in[5];
    const float* rv1 = (const float*)d_in[6];
    const float* W2  = (const float*)d_in[7];
    const float* b2  = (const float*)d_in[8];
    const float* g2  = (const float*)d_in[9];
    const float* bt2 = (const float*)d_in[10];
    const float* rm2 = (const float*)d_in[11];
    const float* rv2 = (const float*)d_in[12];
    const float* Wc  = (const float*)d_in[13];
    const float* bc  = (const float*)d_in[14];
    const int* ei    = (const int*)d_in[15];
    const int* batch = (const int*)d_in[16];
    const int* srcp = ei;
    const int* dstp = ei + NE;

    char* ws = (char*)d_ws;
    int*   ccount = (int*)(ws);                 // NCB
    int*   cbase  = (int*)(ws + 4096);          // NCB+1
    int*   fbase  = (int*)(ws + 8192);          // NCB
    int*   gcur   = (int*)(ws + 12288);         // NCB
    int*   offs   = (int*)(ws + 16384);         // NN
    int*   cntp   = (int*)(ws + 416768);        // NN
    float* dinv   = (float*)(ws + 816768);      // NN
    int*   esf    = (int*)(ws + 1216768);       // NE + 388*NCB ints (~14 MB)
    u16*   hpb    = (u16*)(ws + 15230432);      // (NN+1)*64 bf16 (row NN = zero)
    float* bufB   = (float*)(ws + 28030560);    // NN*64 fp32
    int*   esc    = (int*)(ws + 28030560);      // NE ints — overlaps bufB (dead before agg1 writes)
    float* pool   = (float*)(ws + 53630592);    // 512*64
    float* gcnt   = (float*)(ws + 53761664);    // 512

    // ---- init ----
    hipMemsetAsync(ccount, 0, NCB * 4, stream);
    hipMemsetAsync(hpb + (size_t)NN * 64, 0, 64 * 2, stream);    // sentinel zero row
    hipMemsetAsync(pool, 0, 512 * 64 * 4 + 512 * 4, stream);     // pool + gcnt contiguous

    // ---- CSR build ----
    k_chist<<<512, 256, 0, stream>>>(dstp, ccount);
    k_cscan<<<1, 256, 0, stream>>>(ccount, cbase, fbase, gcur);
    k_p1<<<(NE + P1_CHUNK - 1) / P1_CHUNK, 256, 0, stream>>>(srcp, dstp, gcur, esc);
    k_p2<<<NCB, 256, 0, stream>>>(esc, cbase, fbase, esf, offs, cntp, dinv);

    // ---- layer 1 ----
    k_gemm<128><<<(NN + 127) / 128, 256, 0, stream>>>(x, W1, dinv, hpb, NN);
    k_agg<<<(NN * 64 + 255) / 256, 256, 0, stream>>>(hpb, esf, offs, cntp, dinv, b1, g1, bt1, rm1, rv1, bufB);

    // ---- layer 2 ----
    k_gemm<64><<<(NN + 127) / 128, 256, 0, stream>>>(bufB, W2, dinv, hpb, NN);
    k_agg<<<(NN * 64 + 255) / 256, 256, 0, stream>>>(hpb, esf, offs, cntp, dinv, b2, g2, bt2, rm2, rv2, bufB);

    // ---- pool + classify ----
    k_pool<<<(((NN + 63) / 64) + 3) / 4, 256, 0, stream>>>(bufB, batch, pool, gcnt);
    k_classify<<<NG, 64, 0, stream>>>(pool, gcnt, Wc, bc, (float*)d_out);
}